// Round 21
// baseline (397.629 us; speedup 1.0000x reference)
//
#include <hip/hip_runtime.h>
#include <math.h>

// ---------------- problem constants ----------------
constexpr float RADIUS = 0.025f;
constexpr float R2 = (float)(0.025 * 0.025);   // match JAX f32(0.025^2)
constexpr int   KMAX = 64;
constexpr float BOX  = 0.32f;
constexpr int   G    = 12;            // cell width 26.7mm >= R; +-1-cell scan (proven)
constexpr int   NCELL = G * G * G;    // 1728

typedef unsigned short u16;
typedef unsigned int   u32;
typedef unsigned long long u64;
using bf16x8 = __attribute__((ext_vector_type(8))) short;
using f32x4  = __attribute__((ext_vector_type(4))) float;

// Range-specialized GELU via odd Taylor erf(t)=t*P(t^2), branchless (proven r14+).
__device__ __forceinline__ float gelu_l1(float x) {
    float t = x * 0.70710678118654752440f;
    float s = t * t;
    float p =            1.1283791670955126e-01f;
    p = fmaf(p, s, -3.7612638903183754e-01f);
    p = fmaf(p, s,  1.1283791670955126e+00f);
    return 0.5f * x * fmaf(t, p, 1.0f);
}
__device__ __forceinline__ float gelu_l2(float x) {
    float t = x * 0.70710678118654752440f;
    float s = t * t;
    float p =            5.2239776254421878e-03f;
    p = fmaf(p, s, -2.6866170645131252e-02f);
    p = fmaf(p, s,  1.1283791670955126e-01f);
    p = fmaf(p, s, -3.7612638903183754e-01f);
    p = fmaf(p, s,  1.1283791670955126e+00f);
    return 0.5f * x * fmaf(t, p, 1.0f);
}

__device__ __forceinline__ u16 f2bf(float x) {   // RTNE f32 -> bf16 (finite vals)
    u32 u = __float_as_uint(x);
    return (u16)((u + 0x7FFFu + ((u >> 16) & 1u)) >> 16);
}
__device__ __forceinline__ float bf2f(u16 h) {
    return __uint_as_float(((u32)h) << 16);
}
__device__ __forceinline__ int cell_of(float v) {
    int c = (int)(v * ((float)G / BOX));
    return c < 0 ? 0 : (c >= G ? G - 1 : c);
}

// ---------------- grid build ----------------
__global__ void k_count(const float* __restrict__ y, int n, int* __restrict__ cellCount) {
    int i = blockIdx.x * blockDim.x + threadIdx.x;
    if (i >= n) return;
    int cx = cell_of(y[i * 3 + 0]);
    int cy = cell_of(y[i * 3 + 1]);
    int cz = cell_of(y[i * 3 + 2]);
    atomicAdd(&cellCount[(cz * G + cy) * G + cx], 1);
}

__global__ void k_scan(const int* __restrict__ in, int* __restrict__ out, int n) {
    __shared__ int s[1024];
    int t = threadIdx.x;
    int chunk = (n + 1023) / 1024;
    int lo = t * chunk, hi = min(lo + chunk, n);
    int sum = 0;
    for (int i = lo; i < hi; ++i) sum += in[i];
    s[t] = sum;
    __syncthreads();
    for (int off = 1; off < 1024; off <<= 1) {
        int v = (t >= off) ? s[t - off] : 0;
        __syncthreads();
        s[t] += v;
        __syncthreads();
    }
    int pre = (t == 0) ? 0 : s[t - 1];
    for (int i = lo; i < hi; ++i) { out[i] = pre; pre += in[i]; }
    if (t == 1023) out[n] = s[1023];
}

// pack sorted points as float4{x,y,z,bitcast(idx)} -> 1 vector load / candidate
__global__ void k_scatter(const float* __restrict__ y, int n,
                          const int* __restrict__ cellStart, int* __restrict__ cellFill,
                          float4* __restrict__ sortedP) {
    int i = blockIdx.x * blockDim.x + threadIdx.x;
    if (i >= n) return;
    float px = y[i * 3 + 0], py = y[i * 3 + 1], pz = y[i * 3 + 2];
    int cx = cell_of(px), cy = cell_of(py), cz = cell_of(pz);
    int c = (cz * G + cy) * G + cx;
    int pos = cellStart[c] + atomicAdd(&cellFill[c], 1);
    sortedP[pos] = make_float4(px, py, pz, __int_as_float(i));
}

// ---------------- FUSED neighbor search + pair compaction ----------------
// Wave-per-query (r20-proven ballot append, exact serial order). New this round:
// hits staged in wave-private LDS (no nbrIdx global roundtrip, no d2 stores on
// the hot path); pair slots allocated with ONE device-scope atomicAdd per query;
// pairq/pairsrc/qoff/cnt written directly. Replaces the k_scan(cnt)+k_build_pairs
// dispatches. Inter-query pair placement becomes allocation-order-dependent, but
// every per-pair value and the per-query lane-order sum are unchanged -> d_out
// bit-identical.
__global__ __launch_bounds__(512) void k_neighbors(
    const float4* __restrict__ sortedP, const float* __restrict__ x, int nq,
    const int* __restrict__ cellStart,
    int* __restrict__ pairq, int* __restrict__ pairsrc,
    int* __restrict__ qoff, int* __restrict__ cnt, int* __restrict__ totalPairs) {
    __shared__ int   nbrS[8][KMAX];
    __shared__ float d2S[8][KMAX];
    int wv = threadIdx.x >> 6;
    int q = blockIdx.x * 8 + wv;
    if (q >= nq) return;
    int l = threadIdx.x & 63;
    float qx = x[q * 3 + 0], qy = x[q * 3 + 1], qz = x[q * 3 + 2];
    int cx = cell_of(qx), cy = cell_of(qy), cz = cell_of(qz);
    int c = 0;   // wave-uniform running count of in-radius hits
    u64 below = (1ull << l) - 1ull;

    for (int dz = -1; dz <= 1; ++dz) {
        int z = cz + dz; if (z < 0 || z >= G) continue;
        for (int dy = -1; dy <= 1; ++dy) {
            int yy = cy + dy; if (yy < 0 || yy >= G) continue;
            for (int dx = -1; dx <= 1; ++dx) {
                int xx = cx + dx; if (xx < 0 || xx >= G) continue;
                int cellId = (z * G + yy) * G + xx;
                int s0 = cellStart[cellId], s1 = cellStart[cellId + 1];
                for (int off = s0; off < s1; off += 64) {
                    int u = off + l;
                    bool hit = false;
                    float d2 = 0.f;
                    int j = 0;
                    if (u < s1) {
                        float4 pj = sortedP[u];
                        float ax = pj.x - qx;
                        float ay = pj.y - qy;
                        float az = pj.z - qz;
                        // no-FMA, left-to-right: matches XLA mul-then-reduce exactly
                        d2 = __fmul_rn(ax, ax);
                        d2 = __fadd_rn(d2, __fmul_rn(ay, ay));
                        d2 = __fadd_rn(d2, __fmul_rn(az, az));
                        hit = (d2 <= R2);
                        j = __float_as_int(pj.w);
                    }
                    u64 m = __ballot(hit);
                    if (hit) {
                        int pos = c + (int)__popcll(m & below);
                        if (pos < KMAX) nbrS[wv][pos] = j;
                    }
                    c += (int)__popcll(m);
                }
            }
        }
    }

    int cc = (c <= KMAX) ? c : KMAX;
    if (c > KMAX) {
        // rare overflow: lane 0 re-runs the proven serial top-64 scan into LDS
        if (l == 0) {
            int k2 = 0;
            for (int dz = -1; dz <= 1; ++dz) {
                int z = cz + dz; if (z < 0 || z >= G) continue;
                for (int dy = -1; dy <= 1; ++dy) {
                    int yy = cy + dy; if (yy < 0 || yy >= G) continue;
                    for (int dx = -1; dx <= 1; ++dx) {
                        int xx = cx + dx; if (xx < 0 || xx >= G) continue;
                        int cellId = (z * G + yy) * G + xx;
                        int s0 = cellStart[cellId], s1 = cellStart[cellId + 1];
                        for (int u = s0; u < s1; ++u) {
                            float4 pj = sortedP[u];
                            float ax = pj.x - qx;
                            float ay = pj.y - qy;
                            float az = pj.z - qz;
                            float d2 = __fmul_rn(ax, ax);
                            d2 = __fadd_rn(d2, __fmul_rn(ay, ay));
                            d2 = __fadd_rn(d2, __fmul_rn(az, az));
                            if (d2 <= R2) {
                                int j = __float_as_int(pj.w);
                                if (k2 < KMAX) {
                                    nbrS[wv][k2] = j; d2S[wv][k2] = d2; ++k2;
                                } else {
                                    int mi = 0; float md = d2S[wv][0];
                                    for (int t2 = 1; t2 < KMAX; ++t2) {
                                        float v = d2S[wv][t2];
                                        if (v > md) { md = v; mi = t2; }
                                    }
                                    if (d2 < md) { nbrS[wv][mi] = j; d2S[wv][mi] = d2; }
                                }
                            }
                        }
                    }
                }
            }
        }
    }
    __builtin_amdgcn_wave_barrier();   // order intra-wave LDS writes before reads

    int base = 0;
    if (l == 0) base = atomicAdd(totalPairs, cc);
    base = __shfl(base, 0, 64);
    if (l < cc) {
        pairq[base + l]   = q;
        pairsrc[base + l] = nbrS[wv][l];
    }
    if (l == 0) { qoff[q] = base; cnt[q] = cc; }
}

// ---------------- W2 -> transposed bf16 hi/lo + packed {b2,W3} image ----------------
__global__ void k_prepw2(const float* __restrict__ W2, u16* __restrict__ Whi, u16* __restrict__ Wlo,
                         const float* __restrict__ b2, const float* __restrict__ W3,
                         float4* __restrict__ b2w3) {
    int idx = blockIdx.x * blockDim.x + threadIdx.x;
    if (idx >= 128 * 256) return;
    int k = idx >> 8, n = idx & 255;
    float v = W2[idx];
    u16 hi = f2bf(v);
    u16 lo = f2bf(v - bf2f(hi));
    Whi[n * 128 + k] = hi;
    Wlo[n * 128 + k] = lo;
    if (idx < 256) {
        b2w3[idx] = make_float4(b2[idx], W3[idx * 3 + 0], W3[idx * 3 + 1], W3[idx * 3 + 2]);
    }
}

// ---------------- MLP: proven 196-us body (r17-r20), one 128-pair tile / block ----------------
// A LDS-staged across a cross-wave barrier; B hi/lo global; transposed 3-product
// MFMA chain; straight-line body fits the (512,4) 128-reg cap exactly (64+64).
// Only change vs r20: P comes from the fused allocator's counter.
__global__ __launch_bounds__(512, 4) void k_mlp(
    const float* __restrict__ y, const float* __restrict__ x,
    const int* __restrict__ pairq, const int* __restrict__ pairsrc,
    const int* __restrict__ totalPairs, int nq,
    const float* __restrict__ W1, const float* __restrict__ b1,
    const u16* __restrict__ W2Thi, const u16* __restrict__ W2Tlo,
    const float4* __restrict__ b2w3, const float* __restrict__ b3,
    float* __restrict__ kvals)
{
    __shared__ float relS[128][4];          // 2 KiB
    __shared__ u16 Ahi[4 * 8 * 64 * 8];     // 32 KiB  [ks][pb][slot][e] (H1 hi)
    __shared__ u16 Alo[4 * 8 * 64 * 8];     // 32 KiB  (aliased as red[8][128][3])

    int P = *totalPairs;
    int base = blockIdx.x * 128;
    if (base >= P) return;
    int t = threadIdx.x;
    int w = t >> 6, l = t & 63;

    // stage rel for 128 pairs (threads 0..127)
    if (t < 128) {
        int pi = base + t;
        float r0 = 0.f, r1 = 0.f, r2 = 0.f;
        if (pi < P) {
            int q = pairq[pi], s = pairsrc[pi];
            r0 = y[s * 3 + 0] - x[q * 3 + 0];
            r1 = y[s * 3 + 1] - x[q * 3 + 1];
            r2 = y[s * 3 + 2] - x[q * 3 + 2];
        }
        relS[t][0] = r0; relS[t][1] = r1; relS[t][2] = r2;
    }
    __syncthreads();

    int ksw = w & 3;      // this wave's k-slice for layer 1
    int pg  = w >> 2;     // this wave's pair-half for layer 1

    // layer 1: wave computes k-chunk [ksw*32, ksw*32+32) for pair p = pg*64 + l
    {
        int p = pg * 64 + l;
        float r0 = relS[p][0], r1 = relS[p][1], r2 = relS[p][2];
        int pb = p >> 4, i = p & 15;
        bf16x8 hv, lv;
        #pragma unroll
        for (int kk = 0; kk < 32; ++kk) {
            int k = ksw * 32 + kk;
            float h = b1[k] + r0 * W1[k] + r1 * W1[128 + k] + r2 * W1[256 + k];
            float g = gelu_l1(h);
            u32 gb = __float_as_uint(g);
            float ghi = __uint_as_float(gb & 0xFFFF0000u);   // truncation split
            hv[kk & 7] = (short)(gb >> 16);
            lv[kk & 7] = (short)f2bf(g - ghi);
            if ((kk & 7) == 7) {
                int slot = i + 16 * (kk >> 3);
                int off = ((ksw * 8 + pb) * 64 + slot) * 8;
                *(bf16x8*)&Ahi[off] = hv;
                *(bf16x8*)&Alo[off] = lv;
            }
        }
    }
    __syncthreads();   // cross-wave: layer 2 reads all k-slices & pair-blocks

    // layer 2: wave w owns units [w*32, w*32+32). D = W2frag x H1frag (transposed).
    f32x4 acc[8][2];
    #pragma unroll
    for (int pb = 0; pb < 8; ++pb)
        #pragma unroll
        for (int ub = 0; ub < 2; ++ub)
            acc[pb][ub] = f32x4{0.f, 0.f, 0.f, 0.f};

    int col = l & 15, krow = l >> 4;
    #pragma unroll
    for (int ks = 0; ks < 4; ++ks) {
        bf16x8 bh[2], bl[2];
        #pragma unroll
        for (int ub = 0; ub < 2; ++ub) {
            int n = w * 32 + ub * 16 + col;
            size_t off = (size_t)n * 128 + ks * 32 + krow * 8;
            bh[ub] = *(const bf16x8*)(W2Thi + off);
            bl[ub] = *(const bf16x8*)(W2Tlo + off);
        }
        #pragma unroll
        for (int pb = 0; pb < 8; ++pb) {
            int off = ((ks * 8 + pb) * 64 + l) * 8;
            bf16x8 ah = *(const bf16x8*)&Ahi[off];
            bf16x8 al = *(const bf16x8*)&Alo[off];
            #pragma unroll
            for (int ub = 0; ub < 2; ++ub) {
                // same three products, same order as rounds 12-20 (operands commuted)
                acc[pb][ub] = __builtin_amdgcn_mfma_f32_16x16x32_bf16(bh[ub], ah, acc[pb][ub], 0, 0, 0);
                acc[pb][ub] = __builtin_amdgcn_mfma_f32_16x16x32_bf16(bl[ub], ah, acc[pb][ub], 0, 0, 0);
                acc[pb][ub] = __builtin_amdgcn_mfma_f32_16x16x32_bf16(bh[ub], al, acc[pb][ub], 0, 0, 0);
            }
        }
    }
    __syncthreads();   // Ahi/Alo reads done -> safe to alias red onto Alo

    float (*red)[128][3] = (float (*)[128][3])Alo;   // 8*128*3*4 = 12 KiB

    // layer 3 (transposed D): lane l holds units u = w*32 + ub*16 + 4*krow + r
    // for pair = pb*16 + col. In-lane sum over 8 units, then 2-stage krow reduce.
    #pragma unroll
    for (int pb = 0; pb < 8; ++pb) {
        float pc0 = 0.f, pc1 = 0.f, pc2 = 0.f;
        #pragma unroll
        for (int ub = 0; ub < 2; ++ub)
            #pragma unroll
            for (int r = 0; r < 4; ++r) {
                int unit = w * 32 + ub * 16 + krow * 4 + r;
                float4 bw = b2w3[unit];
                float g = gelu_l2(acc[pb][ub][r] + bw.x);
                pc0 += g * bw.y;
                pc1 += g * bw.z;
                pc2 += g * bw.w;
            }
        // reduce over krow: lanes l, l^16, l^32 (same col, 4 krow values)
        pc0 += __shfl_xor(pc0, 16, 64);
        pc1 += __shfl_xor(pc1, 16, 64);
        pc2 += __shfl_xor(pc2, 16, 64);
        pc0 += __shfl_xor(pc0, 32, 64);
        pc1 += __shfl_xor(pc1, 32, 64);
        pc2 += __shfl_xor(pc2, 32, 64);
        if (krow == 0) {
            int pair = pb * 16 + col;
            red[w][pair][0] = pc0;
            red[w][pair][1] = pc1;
            red[w][pair][2] = pc2;
        }
    }
    __syncthreads();
    if (t < 384) {
        int p = t / 3, c = t % 3;
        float v = b3[c] + red[0][p][c] + red[1][p][c] + red[2][p][c] + red[3][p][c]
                        + red[4][p][c] + red[5][p][c] + red[6][p][c] + red[7][p][c];
        if (base + p < P) kvals[(size_t)(base + p) * 3 + c] = v;
    }
}

// ---------------- per-query masked mean: wave-per-query (cnt <= 64 = wave) ----
__global__ __launch_bounds__(256) void k_finalize(
    const float* __restrict__ kvals, const int* __restrict__ pairsrc,
    const float* __restrict__ f, const int* __restrict__ qoff,
    const int* __restrict__ cnt, int nq, float* __restrict__ out) {
    int q = blockIdx.x * 4 + (threadIdx.x >> 6);
    if (q >= nq) return;
    int l = threadIdx.x & 63;
    int o = qoff[q], n = cnt[q];
    float s0 = 0.f, s1 = 0.f, s2 = 0.f;
    if (l < n) {
        int src = pairsrc[o + l];
        s0 = kvals[(size_t)(o + l) * 3 + 0] * f[src * 3 + 0];
        s1 = kvals[(size_t)(o + l) * 3 + 1] * f[src * 3 + 1];
        s2 = kvals[(size_t)(o + l) * 3 + 2] * f[src * 3 + 2];
    }
    #pragma unroll
    for (int off = 1; off < 64; off <<= 1) {
        s0 += __shfl_xor(s0, off, 64);
        s1 += __shfl_xor(s1, off, 64);
        s2 += __shfl_xor(s2, off, 64);
    }
    if (l == 0) {
        float d = (n > 0) ? (float)n : 1.0f;
        out[q * 3 + 0] = s0 / d;
        out[q * 3 + 1] = s1 / d;
        out[q * 3 + 2] = s2 / d;
    }
}

// ---------------- launch ----------------
extern "C" void kernel_launch(void* const* d_in, const int* in_sizes, int n_in,
                              void* d_out, int out_size, void* d_ws, size_t ws_size,
                              hipStream_t stream) {
    const float* rom_ic = (const float*)d_in[0];
    const float* fom_ic = (const float*)d_in[1];
    const float* rom_f  = (const float*)d_in[2];
    const float* W1 = (const float*)d_in[3];
    const float* b1 = (const float*)d_in[4];
    const float* W2 = (const float*)d_in[5];
    const float* b2 = (const float*)d_in[6];
    const float* W3 = (const float*)d_in[7];
    const float* b3 = (const float*)d_in[8];
    float* out = (float*)d_out;

    int n  = in_sizes[0] / 3;
    int nq = in_sizes[1] / 3;

    char* p = (char*)d_ws;
    auto alloc = [&](size_t bytes) -> void* {
        void* r = (void*)p;
        p += (bytes + 255) & ~(size_t)255;
        return r;
    };
    int*    cellCount  = (int*)alloc(NCELL * 4);
    int*    cellFill   = (int*)alloc(NCELL * 4);
    int*    cellStart  = (int*)alloc((NCELL + 1) * 4);
    float4* sortedP    = (float4*)alloc((size_t)n * 16);
    int*    cnt        = (int*)alloc((size_t)nq * 4);
    int*    qoff       = (int*)alloc((size_t)nq * 4);
    int*    pairq      = (int*)alloc((size_t)nq * KMAX * 4);
    int*    pairsrc    = (int*)alloc((size_t)nq * KMAX * 4);
    float*  kvals      = (float*)alloc((size_t)nq * KMAX * 3 * 4);
    u16*    W2Thi      = (u16*)alloc(128 * 256 * 2);
    u16*    W2Tlo      = (u16*)alloc(128 * 256 * 2);
    float4* b2w3       = (float4*)alloc(256 * 16);
    int*    totalPairs = (int*)alloc(256);

    hipMemsetAsync(cellCount, 0, NCELL * 4, stream);
    hipMemsetAsync(cellFill,  0, NCELL * 4, stream);
    hipMemsetAsync(totalPairs, 0, 4, stream);

    int blocksN = (n + 255) / 256;

    k_count<<<blocksN, 256, 0, stream>>>(rom_ic, n, cellCount);
    k_scan<<<1, 1024, 0, stream>>>(cellCount, cellStart, NCELL);
    k_scatter<<<blocksN, 256, 0, stream>>>(rom_ic, n, cellStart, cellFill, sortedP);
    k_prepw2<<<128, 256, 0, stream>>>(W2, W2Thi, W2Tlo, b2, W3, b2w3);
    k_neighbors<<<(nq + 7) / 8, 512, 0, stream>>>(sortedP, fom_ic, nq, cellStart,
                                                  pairq, pairsrc, qoff, cnt, totalPairs);
    // 128 pairs per block; worst-case tiles = nq*KMAX/128 = nq/2 (excess early-exit)
    k_mlp<<<(nq + 1) / 2, 512, 0, stream>>>(rom_ic, fom_ic, pairq, pairsrc, totalPairs, nq,
                                            W1, b1, W2Thi, W2Tlo, b2w3, b3, kvals);
    k_finalize<<<(nq + 3) / 4, 256, 0, stream>>>(kvals, pairsrc, rom_f, qoff, cnt, nq, out);
}

// Round 22
// 255.491 us; speedup vs baseline: 1.5563x; 1.5563x over previous
//
#include <hip/hip_runtime.h>
#include <math.h>

// ---------------- problem constants ----------------
constexpr float RADIUS = 0.025f;
constexpr float R2 = (float)(0.025 * 0.025);   // match JAX f32(0.025^2)
constexpr int   KMAX = 64;
constexpr float BOX  = 0.32f;
constexpr int   G    = 12;            // cell width 26.7mm >= R; +-1-cell scan (proven)
constexpr int   NCELL = G * G * G;    // 1728

typedef unsigned short u16;
typedef unsigned int   u32;
typedef unsigned long long u64;
using bf16x8 = __attribute__((ext_vector_type(8))) short;
using f32x4  = __attribute__((ext_vector_type(4))) float;

// Range-specialized GELU via odd Taylor erf(t)=t*P(t^2), branchless (proven r14+).
__device__ __forceinline__ float gelu_l1(float x) {
    float t = x * 0.70710678118654752440f;
    float s = t * t;
    float p =            1.1283791670955126e-01f;
    p = fmaf(p, s, -3.7612638903183754e-01f);
    p = fmaf(p, s,  1.1283791670955126e+00f);
    return 0.5f * x * fmaf(t, p, 1.0f);
}
__device__ __forceinline__ float gelu_l2(float x) {
    float t = x * 0.70710678118654752440f;
    float s = t * t;
    float p =            5.2239776254421878e-03f;
    p = fmaf(p, s, -2.6866170645131252e-02f);
    p = fmaf(p, s,  1.1283791670955126e-01f);
    p = fmaf(p, s, -3.7612638903183754e-01f);
    p = fmaf(p, s,  1.1283791670955126e+00f);
    return 0.5f * x * fmaf(t, p, 1.0f);
}

__device__ __forceinline__ u16 f2bf(float x) {   // RTNE f32 -> bf16 (finite vals)
    u32 u = __float_as_uint(x);
    return (u16)((u + 0x7FFFu + ((u >> 16) & 1u)) >> 16);
}
__device__ __forceinline__ float bf2f(u16 h) {
    return __uint_as_float(((u32)h) << 16);
}
__device__ __forceinline__ int cell_of(float v) {
    int c = (int)(v * ((float)G / BOX));
    return c < 0 ? 0 : (c >= G ? G - 1 : c);
}

// ---------------- grid build ----------------
__global__ void k_count(const float* __restrict__ y, int n, int* __restrict__ cellCount) {
    int i = blockIdx.x * blockDim.x + threadIdx.x;
    if (i >= n) return;
    int cx = cell_of(y[i * 3 + 0]);
    int cy = cell_of(y[i * 3 + 1]);
    int cz = cell_of(y[i * 3 + 2]);
    atomicAdd(&cellCount[(cz * G + cy) * G + cx], 1);
}

__global__ void k_scan(const int* __restrict__ in, int* __restrict__ out, int n) {
    __shared__ int s[1024];
    int t = threadIdx.x;
    int chunk = (n + 1023) / 1024;
    int lo = t * chunk, hi = min(lo + chunk, n);
    int sum = 0;
    for (int i = lo; i < hi; ++i) sum += in[i];
    s[t] = sum;
    __syncthreads();
    for (int off = 1; off < 1024; off <<= 1) {
        int v = (t >= off) ? s[t - off] : 0;
        __syncthreads();
        s[t] += v;
        __syncthreads();
    }
    int pre = (t == 0) ? 0 : s[t - 1];
    for (int i = lo; i < hi; ++i) { out[i] = pre; pre += in[i]; }
    if (t == 1023) out[n] = s[1023];
}

// pack sorted points as float4{x,y,z,bitcast(idx)} -> 1 vector load / candidate
__global__ void k_scatter(const float* __restrict__ y, int n,
                          const int* __restrict__ cellStart, int* __restrict__ cellFill,
                          float4* __restrict__ sortedP) {
    int i = blockIdx.x * blockDim.x + threadIdx.x;
    if (i >= n) return;
    float px = y[i * 3 + 0], py = y[i * 3 + 1], pz = y[i * 3 + 2];
    int cx = cell_of(px), cy = cell_of(py), cz = cell_of(pz);
    int c = (cz * G + cy) * G + cx;
    int pos = cellStart[c] + atomicAdd(&cellFill[c], 1);
    sortedP[pos] = make_float4(px, py, pz, __int_as_float(i));
}

// ---------------- neighbor search: WAVE-per-query, ballot append (r20-proven) ----------------
// One 64-lane wave per query. Cells iterated in the same dz/dy/dx order as the
// serial kernel; within a cell, lane (u-s0) tests candidate u -> ballot+prefix
// popcount assigns slots in EXACT serial order, so the stored first-64 set is
// bit-identical. d2 uses the same no-FMA left-to-right ops. The rare >64 case
// falls back to the proven serial replacement scan on lane 0.
__global__ __launch_bounds__(512) void k_neighbors(
    const float4* __restrict__ sortedP, const float* __restrict__ x, int nq,
    const int* __restrict__ cellStart,
    int* __restrict__ nbrIdx, float* __restrict__ nbrD2,
    int* __restrict__ cnt) {
    int q = blockIdx.x * 8 + (threadIdx.x >> 6);
    if (q >= nq) return;
    int l = threadIdx.x & 63;
    float qx = x[q * 3 + 0], qy = x[q * 3 + 1], qz = x[q * 3 + 2];
    int cx = cell_of(qx), cy = cell_of(qy), cz = cell_of(qz);
    int c = 0;   // wave-uniform running count of in-radius hits
    int*   my  = nbrIdx + (size_t)q * KMAX;
    float* myd = nbrD2  + (size_t)q * KMAX;
    u64 below = (1ull << l) - 1ull;

    for (int dz = -1; dz <= 1; ++dz) {
        int z = cz + dz; if (z < 0 || z >= G) continue;
        for (int dy = -1; dy <= 1; ++dy) {
            int yy = cy + dy; if (yy < 0 || yy >= G) continue;
            for (int dx = -1; dx <= 1; ++dx) {
                int xx = cx + dx; if (xx < 0 || xx >= G) continue;
                int cellId = (z * G + yy) * G + xx;
                int s0 = cellStart[cellId], s1 = cellStart[cellId + 1];
                for (int off = s0; off < s1; off += 64) {
                    int u = off + l;
                    bool hit = false;
                    float d2 = 0.f;
                    int j = 0;
                    if (u < s1) {
                        float4 pj = sortedP[u];
                        float ax = pj.x - qx;
                        float ay = pj.y - qy;
                        float az = pj.z - qz;
                        d2 = __fmul_rn(ax, ax);
                        d2 = __fadd_rn(d2, __fmul_rn(ay, ay));
                        d2 = __fadd_rn(d2, __fmul_rn(az, az));
                        hit = (d2 <= R2);
                        j = __float_as_int(pj.w);
                    }
                    u64 m = __ballot(hit);
                    if (hit) {
                        int pos = c + (int)__popcll(m & below);
                        if (pos < KMAX) { my[pos] = j; myd[pos] = d2; }
                    }
                    c += (int)__popcll(m);
                }
            }
        }
    }

    if (c <= KMAX) {
        if (l == 0) cnt[q] = c;
        return;
    }
    // overflow (>64 in radius): lane 0 re-runs the proven serial top-64 scan
    if (l == 0) {
        int cc = 0;
        for (int dz = -1; dz <= 1; ++dz) {
            int z = cz + dz; if (z < 0 || z >= G) continue;
            for (int dy = -1; dy <= 1; ++dy) {
                int yy = cy + dy; if (yy < 0 || yy >= G) continue;
                for (int dx = -1; dx <= 1; ++dx) {
                    int xx = cx + dx; if (xx < 0 || xx >= G) continue;
                    int cellId = (z * G + yy) * G + xx;
                    int s0 = cellStart[cellId], s1 = cellStart[cellId + 1];
                    for (int u = s0; u < s1; ++u) {
                        float4 pj = sortedP[u];
                        float ax = pj.x - qx;
                        float ay = pj.y - qy;
                        float az = pj.z - qz;
                        float d2 = __fmul_rn(ax, ax);
                        d2 = __fadd_rn(d2, __fmul_rn(ay, ay));
                        d2 = __fadd_rn(d2, __fmul_rn(az, az));
                        if (d2 <= R2) {
                            int j = __float_as_int(pj.w);
                            if (cc < KMAX) {
                                my[cc] = j; myd[cc] = d2; ++cc;
                            } else {
                                int mi = 0; float md = myd[0];
                                for (int t2 = 1; t2 < KMAX; ++t2) {
                                    float v = myd[t2];
                                    if (v > md) { md = v; mi = t2; }
                                }
                                if (d2 < md) { my[mi] = j; myd[mi] = d2; }
                            }
                        }
                    }
                }
            }
        }
        cnt[q] = cc;
    }
}

// wave-per-query pair compaction (cnt <= 64 = wave size)
__global__ __launch_bounds__(256) void k_build_pairs(
    const int* __restrict__ nbrIdx, const int* __restrict__ cnt,
    const int* __restrict__ qoff, int nq,
    int* __restrict__ pairq, int* __restrict__ pairsrc) {
    int q = blockIdx.x * 4 + (threadIdx.x >> 6);
    if (q >= nq) return;
    int l = threadIdx.x & 63;
    int o = qoff[q], n = cnt[q];
    if (l < n) {
        pairq[o + l]   = q;
        pairsrc[o + l] = nbrIdx[(size_t)q * KMAX + l];
    }
}

// ---------------- W2 -> transposed bf16 hi/lo + packed {b2,W3} image ----------------
__global__ void k_prepw2(const float* __restrict__ W2, u16* __restrict__ Whi, u16* __restrict__ Wlo,
                         const float* __restrict__ b2, const float* __restrict__ W3,
                         float4* __restrict__ b2w3) {
    int idx = blockIdx.x * blockDim.x + threadIdx.x;
    if (idx >= 128 * 256) return;
    int k = idx >> 8, n = idx & 255;
    float v = W2[idx];
    u16 hi = f2bf(v);
    u16 lo = f2bf(v - bf2f(hi));
    Whi[n * 128 + k] = hi;
    Wlo[n * 128 + k] = lo;
    if (idx < 256) {
        b2w3[idx] = make_float4(b2[idx], W3[idx * 3 + 0], W3[idx * 3 + 1], W3[idx * 3 + 2]);
    }
}

// ---------------- MLP: proven 196-us body, one 128-pair tile / block ----------------
// A LDS-staged across a cross-wave barrier; B hi/lo global; transposed 3-product
// MFMA chain; straight-line body fits the (512,4) 128-reg cap exactly (64+64).
__global__ __launch_bounds__(512, 4) void k_mlp(
    const float* __restrict__ y, const float* __restrict__ x,
    const int* __restrict__ pairq, const int* __restrict__ pairsrc,
    const int* __restrict__ qoff, int nq,
    const float* __restrict__ W1, const float* __restrict__ b1,
    const u16* __restrict__ W2Thi, const u16* __restrict__ W2Tlo,
    const float4* __restrict__ b2w3, const float* __restrict__ b3,
    float* __restrict__ kvals)
{
    __shared__ float relS[128][4];          // 2 KiB
    __shared__ u16 Ahi[4 * 8 * 64 * 8];     // 32 KiB  [ks][pb][slot][e] (H1 hi)
    __shared__ u16 Alo[4 * 8 * 64 * 8];     // 32 KiB  (aliased as red[8][128][3])

    int P = qoff[nq];
    int base = blockIdx.x * 128;
    if (base >= P) return;
    int t = threadIdx.x;
    int w = t >> 6, l = t & 63;

    // stage rel for 128 pairs (threads 0..127)
    if (t < 128) {
        int pi = base + t;
        float r0 = 0.f, r1 = 0.f, r2 = 0.f;
        if (pi < P) {
            int q = pairq[pi], s = pairsrc[pi];
            r0 = y[s * 3 + 0] - x[q * 3 + 0];
            r1 = y[s * 3 + 1] - x[q * 3 + 1];
            r2 = y[s * 3 + 2] - x[q * 3 + 2];
        }
        relS[t][0] = r0; relS[t][1] = r1; relS[t][2] = r2;
    }
    __syncthreads();

    int ksw = w & 3;      // this wave's k-slice for layer 1
    int pg  = w >> 2;     // this wave's pair-half for layer 1

    // layer 1: wave computes k-chunk [ksw*32, ksw*32+32) for pair p = pg*64 + l
    {
        int p = pg * 64 + l;
        float r0 = relS[p][0], r1 = relS[p][1], r2 = relS[p][2];
        int pb = p >> 4, i = p & 15;
        bf16x8 hv, lv;
        #pragma unroll
        for (int kk = 0; kk < 32; ++kk) {
            int k = ksw * 32 + kk;
            float h = b1[k] + r0 * W1[k] + r1 * W1[128 + k] + r2 * W1[256 + k];
            float g = gelu_l1(h);
            u32 gb = __float_as_uint(g);
            float ghi = __uint_as_float(gb & 0xFFFF0000u);   // truncation split
            hv[kk & 7] = (short)(gb >> 16);
            lv[kk & 7] = (short)f2bf(g - ghi);
            if ((kk & 7) == 7) {
                int slot = i + 16 * (kk >> 3);
                int off = ((ksw * 8 + pb) * 64 + slot) * 8;
                *(bf16x8*)&Ahi[off] = hv;
                *(bf16x8*)&Alo[off] = lv;
            }
        }
    }
    __syncthreads();   // cross-wave: layer 2 reads all k-slices & pair-blocks

    // layer 2: wave w owns units [w*32, w*32+32). D = W2frag x H1frag (transposed).
    f32x4 acc[8][2];
    #pragma unroll
    for (int pb = 0; pb < 8; ++pb)
        #pragma unroll
        for (int ub = 0; ub < 2; ++ub)
            acc[pb][ub] = f32x4{0.f, 0.f, 0.f, 0.f};

    int col = l & 15, krow = l >> 4;
    #pragma unroll
    for (int ks = 0; ks < 4; ++ks) {
        bf16x8 bh[2], bl[2];
        #pragma unroll
        for (int ub = 0; ub < 2; ++ub) {
            int n = w * 32 + ub * 16 + col;
            size_t off = (size_t)n * 128 + ks * 32 + krow * 8;
            bh[ub] = *(const bf16x8*)(W2Thi + off);
            bl[ub] = *(const bf16x8*)(W2Tlo + off);
        }
        #pragma unroll
        for (int pb = 0; pb < 8; ++pb) {
            int off = ((ks * 8 + pb) * 64 + l) * 8;
            bf16x8 ah = *(const bf16x8*)&Ahi[off];
            bf16x8 al = *(const bf16x8*)&Alo[off];
            #pragma unroll
            for (int ub = 0; ub < 2; ++ub) {
                acc[pb][ub] = __builtin_amdgcn_mfma_f32_16x16x32_bf16(bh[ub], ah, acc[pb][ub], 0, 0, 0);
                acc[pb][ub] = __builtin_amdgcn_mfma_f32_16x16x32_bf16(bl[ub], ah, acc[pb][ub], 0, 0, 0);
                acc[pb][ub] = __builtin_amdgcn_mfma_f32_16x16x32_bf16(bh[ub], al, acc[pb][ub], 0, 0, 0);
            }
        }
    }
    __syncthreads();   // Ahi/Alo reads done -> safe to alias red onto Alo

    float (*red)[128][3] = (float (*)[128][3])Alo;   // 8*128*3*4 = 12 KiB

    // layer 3 (transposed D): lane l holds units u = w*32 + ub*16 + 4*krow + r
    // for pair = pb*16 + col. In-lane sum over 8 units, then 2-stage krow reduce.
    #pragma unroll
    for (int pb = 0; pb < 8; ++pb) {
        float pc0 = 0.f, pc1 = 0.f, pc2 = 0.f;
        #pragma unroll
        for (int ub = 0; ub < 2; ++ub)
            #pragma unroll
            for (int r = 0; r < 4; ++r) {
                int unit = w * 32 + ub * 16 + krow * 4 + r;
                float4 bw = b2w3[unit];
                float g = gelu_l2(acc[pb][ub][r] + bw.x);
                pc0 += g * bw.y;
                pc1 += g * bw.z;
                pc2 += g * bw.w;
            }
        pc0 += __shfl_xor(pc0, 16, 64);
        pc1 += __shfl_xor(pc1, 16, 64);
        pc2 += __shfl_xor(pc2, 16, 64);
        pc0 += __shfl_xor(pc0, 32, 64);
        pc1 += __shfl_xor(pc1, 32, 64);
        pc2 += __shfl_xor(pc2, 32, 64);
        if (krow == 0) {
            int pair = pb * 16 + col;
            red[w][pair][0] = pc0;
            red[w][pair][1] = pc1;
            red[w][pair][2] = pc2;
        }
    }
    __syncthreads();
    if (t < 384) {
        int p = t / 3, c = t % 3;
        float v = b3[c] + red[0][p][c] + red[1][p][c] + red[2][p][c] + red[3][p][c]
                        + red[4][p][c] + red[5][p][c] + red[6][p][c] + red[7][p][c];
        if (base + p < P) kvals[(size_t)(base + p) * 3 + c] = v;
    }
}

// ---------------- per-query masked mean: wave-per-query (cnt <= 64 = wave) ----
__global__ __launch_bounds__(256) void k_finalize(
    const float* __restrict__ kvals, const int* __restrict__ pairsrc,
    const float* __restrict__ f, const int* __restrict__ qoff,
    const int* __restrict__ cnt, int nq, float* __restrict__ out) {
    int q = blockIdx.x * 4 + (threadIdx.x >> 6);
    if (q >= nq) return;
    int l = threadIdx.x & 63;
    int o = qoff[q], n = cnt[q];
    float s0 = 0.f, s1 = 0.f, s2 = 0.f;
    if (l < n) {
        int src = pairsrc[o + l];
        s0 = kvals[(size_t)(o + l) * 3 + 0] * f[src * 3 + 0];
        s1 = kvals[(size_t)(o + l) * 3 + 1] * f[src * 3 + 1];
        s2 = kvals[(size_t)(o + l) * 3 + 2] * f[src * 3 + 2];
    }
    #pragma unroll
    for (int off = 1; off < 64; off <<= 1) {
        s0 += __shfl_xor(s0, off, 64);
        s1 += __shfl_xor(s1, off, 64);
        s2 += __shfl_xor(s2, off, 64);
    }
    if (l == 0) {
        float d = (n > 0) ? (float)n : 1.0f;
        out[q * 3 + 0] = s0 / d;
        out[q * 3 + 1] = s1 / d;
        out[q * 3 + 2] = s2 / d;
    }
}

// ---------------- launch ----------------
extern "C" void kernel_launch(void* const* d_in, const int* in_sizes, int n_in,
                              void* d_out, int out_size, void* d_ws, size_t ws_size,
                              hipStream_t stream) {
    const float* rom_ic = (const float*)d_in[0];
    const float* fom_ic = (const float*)d_in[1];
    const float* rom_f  = (const float*)d_in[2];
    const float* W1 = (const float*)d_in[3];
    const float* b1 = (const float*)d_in[4];
    const float* W2 = (const float*)d_in[5];
    const float* b2 = (const float*)d_in[6];
    const float* W3 = (const float*)d_in[7];
    const float* b3 = (const float*)d_in[8];
    float* out = (float*)d_out;

    int n  = in_sizes[0] / 3;
    int nq = in_sizes[1] / 3;

    char* p = (char*)d_ws;
    auto alloc = [&](size_t bytes) -> void* {
        void* r = (void*)p;
        p += (bytes + 255) & ~(size_t)255;
        return r;
    };
    int*    cellCount = (int*)alloc(NCELL * 4);
    int*    cellFill  = (int*)alloc(NCELL * 4);
    int*    cellStart = (int*)alloc((NCELL + 1) * 4);
    float4* sortedP   = (float4*)alloc((size_t)n * 16);
    int*    nbrIdx    = (int*)alloc((size_t)nq * KMAX * 4);
    float*  nbrD2     = (float*)alloc((size_t)nq * KMAX * 4);
    int*    cnt       = (int*)alloc((size_t)nq * 4);
    int*    qoff      = (int*)alloc(((size_t)nq + 1) * 4);
    int*    pairq     = (int*)alloc((size_t)nq * KMAX * 4);
    int*    pairsrc   = (int*)alloc((size_t)nq * KMAX * 4);
    float*  kvals     = (float*)alloc((size_t)nq * KMAX * 3 * 4);
    u16*    W2Thi     = (u16*)alloc(128 * 256 * 2);
    u16*    W2Tlo     = (u16*)alloc(128 * 256 * 2);
    float4* b2w3      = (float4*)alloc(256 * 16);

    hipMemsetAsync(cellCount, 0, NCELL * 4, stream);
    hipMemsetAsync(cellFill,  0, NCELL * 4, stream);

    int blocksN  = (n + 255) / 256;

    k_count<<<blocksN, 256, 0, stream>>>(rom_ic, n, cellCount);
    k_scan<<<1, 1024, 0, stream>>>(cellCount, cellStart, NCELL);
    k_scatter<<<blocksN, 256, 0, stream>>>(rom_ic, n, cellStart, cellFill, sortedP);
    k_prepw2<<<128, 256, 0, stream>>>(W2, W2Thi, W2Tlo, b2, W3, b2w3);
    k_neighbors<<<(nq + 7) / 8, 512, 0, stream>>>(sortedP, fom_ic, nq, cellStart,
                                                  nbrIdx, nbrD2, cnt);
    k_scan<<<1, 1024, 0, stream>>>(cnt, qoff, nq);
    k_build_pairs<<<(nq + 3) / 4, 256, 0, stream>>>(nbrIdx, cnt, qoff, nq, pairq, pairsrc);
    // 128 pairs per block; max tiles = nq*KMAX/128 = nq/2 (excess blocks early-exit)
    k_mlp<<<(nq + 1) / 2, 512, 0, stream>>>(rom_ic, fom_ic, pairq, pairsrc, qoff, nq,
                                            W1, b1, W2Thi, W2Tlo, b2w3, b3, kvals);
    k_finalize<<<(nq + 3) / 4, 256, 0, stream>>>(kvals, pairsrc, rom_f, qoff, cnt, nq, out);
}